// Round 1
// baseline (264.565 us; speedup 1.0000x reference)
//
#include <hip/hip_runtime.h>

// Problem: img [B=256, C=3, H=224, W=224] f32; zero a 32x32 square per batch
// (all channels), copy the rest. Memory-bound: ~308 MB -> ~49 us floor @6.3 TB/s.
//
// Measured 255.8 us total = ~190 us harness re-poison fills (2x ~95 us, fixed)
// + ~65 us kernel. This version targets the kernel-side ~16 us gap:
//  - one block per (plane, chunk): b/y0/x0 become wave-uniform s_loads
//  - 7 float4 per thread, all loads issued before first use (MLP=7)
//  - non-temporal stores: keep the 154 MB write stream out of L2/L3 so the
//    input can stay Infinity-Cache-resident across graph replays
//  - exact grid coverage, no tail branch

#define SQ 32
#define B_ 256
#define C_ 3
#define H_ 224
#define W_ 224

#define W4 (W_ / 4)               // 56 float4 per row
#define PLANE4 (H_ * W4)          // 12544 float4 per (b,c) plane
#define SPLIT 7                   // chunks per plane
#define CHUNK4 (PLANE4 / SPLIT)   // 1792 float4 per chunk
#define TPB 256
#define ITERS (CHUNK4 / TPB)      // 7 float4 per thread, exact

typedef float v4f __attribute__((ext_vector_type(4)));

__global__ __launch_bounds__(TPB) void rsd_kernel(const v4f* __restrict__ img,
                                                  const int* __restrict__ y_idx,
                                                  const int* __restrict__ x_idx,
                                                  v4f* __restrict__ out) {
    const int blk   = (int)blockIdx.x;
    const int plane = blk / SPLIT;           // uniform -> SALU (b*C + c)
    const int chunk = blk - plane * SPLIT;   // uniform
    const int b     = plane / C_;            // uniform

    const int y0 = y_idx[b];                 // uniform -> s_load
    const int x0 = x_idx[b];                 // uniform -> s_load

    const int base4 = plane * PLANE4 + chunk * CHUNK4;
    const int t     = (int)threadIdx.x;

    // Issue all 7 loads before any dependent use: 7 outstanding per thread.
    v4f v[ITERS];
#pragma unroll
    for (int k = 0; k < ITERS; ++k)
        v[k] = img[base4 + k * TPB + t];

#pragma unroll
    for (int k = 0; k < ITERS; ++k) {
        const int o4 = chunk * CHUNK4 + k * TPB + t;  // float4 offset in plane
        const int h  = o4 / W4;                       // row (magic-mul)
        const int w  = (o4 - h * W4) << 2;            // column of lane elem 0
        const bool rin = (unsigned)(h - y0) < SQ;     // row inside square?
        const int  cx  = w - x0;
        if (rin) {
            if ((unsigned)(cx + 0) < SQ) v[k].x = 0.0f;
            if ((unsigned)(cx + 1) < SQ) v[k].y = 0.0f;
            if ((unsigned)(cx + 2) < SQ) v[k].z = 0.0f;
            if ((unsigned)(cx + 3) < SQ) v[k].w = 0.0f;
        }
        __builtin_nontemporal_store(v[k], &out[base4 + k * TPB + t]);
    }
}

extern "C" void kernel_launch(void* const* d_in, const int* in_sizes, int n_in,
                              void* d_out, int out_size, void* d_ws, size_t ws_size,
                              hipStream_t stream) {
    const v4f* img  = (const v4f*)d_in[0];
    const int* yidx = (const int*)d_in[1];
    const int* xidx = (const int*)d_in[2];
    v4f*       out  = (v4f*)d_out;

    // 256 * 3 * 7 = 5376 blocks x 256 threads x 7 float4 = 9,633,792 float4
    // = exactly out_size / 16. No tail.
    rsd_kernel<<<dim3(B_ * C_ * SPLIT), TPB, 0, stream>>>(img, yidx, xidx, out);
}

// Round 2
// 262.639 us; speedup vs baseline: 1.0073x; 1.0073x over previous
//
#include <hip/hip_runtime.h>

// Problem: img [B=256, C=3, H=224, W=224] f32; zero a 32x32 square per batch
// (all channels), copy the rest. Memory-bound: ~308 MB -> ~49 us floor @6.3 TB/s.
//
// Round-1 post-mortem: VGPR_Count=24 proved the 7-deep load batch was sunk
// back into the store loop (MLP=1), and nontemporal stores regressed BW
// (91.8 us, 3.35 TB/s). This version:
//  - sched_barrier(0) pins all 7 loads before the mask/store loop
//    (counted vmcnt drain, 7 outstanding loads/thread)
//  - plain stores (fills hit 6.6 TB/s with plain stores)
//  - keeps: uniform s_load of y0/x0, exact-coverage grid, no tail

#define SQ 32
#define B_ 256
#define C_ 3
#define H_ 224
#define W_ 224

#define W4 (W_ / 4)               // 56 float4 per row
#define PLANE4 (H_ * W4)          // 12544 float4 per (b,c) plane
#define SPLIT 7                   // chunks per plane
#define CHUNK4 (PLANE4 / SPLIT)   // 1792 float4 per chunk
#define TPB 256
#define ITERS (CHUNK4 / TPB)      // 7 float4 per thread, exact

typedef float v4f __attribute__((ext_vector_type(4)));

__global__ __launch_bounds__(TPB) void rsd_kernel(const v4f* __restrict__ img,
                                                  const int* __restrict__ y_idx,
                                                  const int* __restrict__ x_idx,
                                                  v4f* __restrict__ out) {
    const int blk   = (int)blockIdx.x;
    const int plane = blk / SPLIT;           // uniform (b*C + c)
    const int chunk = blk - plane * SPLIT;   // uniform
    const int b     = plane / C_;            // uniform

    const int y0 = y_idx[b];                 // uniform -> s_load
    const int x0 = x_idx[b];                 // uniform -> s_load

    const int t     = (int)threadIdx.x;
    const int base4 = plane * PLANE4 + chunk * CHUNK4 + t;

    // Issue all 7 loads; keep them ALL in flight.
    v4f v[ITERS];
#pragma unroll
    for (int k = 0; k < ITERS; ++k)
        v[k] = img[base4 + k * TPB];

    // Fence the scheduler: nothing from below may move above (and vice versa).
    // Without this, round 1 showed the compiler sinks each load to just
    // before its store -> MLP collapses to 1.
    __builtin_amdgcn_sched_barrier(0);

#pragma unroll
    for (int k = 0; k < ITERS; ++k) {
        const int o4 = chunk * CHUNK4 + k * TPB + t;  // float4 offset in plane
        const int h  = o4 / W4;                       // row (magic-mul)
        const int w  = (o4 - h * W4) << 2;            // column of lane elem 0
        const int cx = w - x0;
        if ((unsigned)(h - y0) < SQ) {                // row inside square?
            if ((unsigned)(cx + 0) < SQ) v[k].x = 0.0f;
            if ((unsigned)(cx + 1) < SQ) v[k].y = 0.0f;
            if ((unsigned)(cx + 2) < SQ) v[k].z = 0.0f;
            if ((unsigned)(cx + 3) < SQ) v[k].w = 0.0f;
        }
        out[base4 + k * TPB] = v[k];
    }
}

extern "C" void kernel_launch(void* const* d_in, const int* in_sizes, int n_in,
                              void* d_out, int out_size, void* d_ws, size_t ws_size,
                              hipStream_t stream) {
    const v4f* img  = (const v4f*)d_in[0];
    const int* yidx = (const int*)d_in[1];
    const int* xidx = (const int*)d_in[2];
    v4f*       out  = (v4f*)d_out;

    // 256 * 3 * 7 = 5376 blocks x 256 threads x 7 float4 = 9,633,792 float4
    // = exactly out_size / 16. No tail.
    rsd_kernel<<<dim3(B_ * C_ * SPLIT), TPB, 0, stream>>>(img, yidx, xidx, out);
}